// Round 5
// baseline (764.279 us; speedup 1.0000x reference)
//
#include <hip/hip_runtime.h>

#define N_NODES 100000
#define N_EDGES 1000000
#define EPS 1e-5f
#define SLOPE 0.01f
#define NBLK 391    // ceil(N_NODES/256)
#define GBLK 1563   // ceil(N_NODES/64): gather, 64 nodes/block, 5 thr/node
#define DBINS 64    // degree bins for counting sort (deg clamped to 63)
#define SROW 84     // LDS row stride (floats) for 80-float acc, 16B aligned

// ---------------------------------------------------------------------------
// ws layout: eef(float4 E) | rank(E) | esrc(E) | hist(N)+stats(32) [zeroed] |
//            row_part(N) | nodeorder(N) | blockhist(NBLK*64) |
//            blockbase(NBLK*64) | bsum(512) | bsum_ex(512) | binoff(64)
// total ~25.5 MB
// ---------------------------------------------------------------------------

// K1: per-edge rank within dst bucket; hist becomes in-degree.
__global__ __launch_bounds__(256) void rank_kernel(
    const int* __restrict__ edge_index,
    int* __restrict__ hist,
    int* __restrict__ rank)
{
    int eid = blockIdx.x * 256 + threadIdx.x;
    if (eid >= N_EDGES) return;
    int dst = edge_index[N_EDGES + eid];
    rank[eid] = atomicAdd(hist + dst, 1);
}

// K2: block-local exclusive scan of hist + block sums.
__global__ __launch_bounds__(256) void scan1_kernel(
    const int* __restrict__ hist,
    int* __restrict__ row_part,
    int* __restrict__ bsum)
{
    __shared__ int s[256];
    int tid = threadIdx.x;
    int idx = blockIdx.x * 256 + tid;
    int val = (idx < N_NODES) ? hist[idx] : 0;
    s[tid] = val;
    __syncthreads();
    #pragma unroll
    for (int off = 1; off < 256; off <<= 1) {
        int t = (tid >= off) ? s[tid - off] : 0;
        __syncthreads();
        s[tid] += t;
        __syncthreads();
    }
    if (idx < N_NODES) row_part[idx] = s[tid] - val;
    if (tid == 255) bsum[blockIdx.x] = s[255];
}

// K3: exclusive scan of block sums.
__global__ __launch_bounds__(512) void scan2_kernel(
    const int* __restrict__ bsum,
    int* __restrict__ bsum_ex)
{
    __shared__ int s[512];
    int tid = threadIdx.x;
    int val = (tid < NBLK) ? bsum[tid] : 0;
    s[tid] = val;
    __syncthreads();
    #pragma unroll
    for (int off = 1; off < 512; off <<= 1) {
        int t = (tid >= off) ? s[tid - off] : 0;
        __syncthreads();
        s[tid] += t;
        __syncthreads();
    }
    bsum_ex[tid] = s[tid] - val;
}

// K4: scatter edge payload (src, ef) into CSR slot order.
__global__ __launch_bounds__(256) void payload_kernel(
    const int* __restrict__ edge_index,
    const float* __restrict__ efeat,
    const int* __restrict__ rank,
    const int* __restrict__ row_part,
    const int* __restrict__ bsum_ex,
    int* __restrict__ esrc,
    float4* __restrict__ eef)
{
    int eid = blockIdx.x * 256 + threadIdx.x;
    if (eid >= N_EDGES) return;
    int dst = edge_index[N_EDGES + eid];
    int slot = row_part[dst] + bsum_ex[dst >> 8] + rank[eid];
    esrc[slot] = edge_index[eid];
    eef[slot] = *(const float4*)(efeat + (size_t)eid * 4);
}

// K5: per-block degree histogram (LDS-privatized).
__global__ __launch_bounds__(256) void degsort1_kernel(
    const int* __restrict__ hist,
    int* __restrict__ blockhist)
{
    __shared__ int h[DBINS];
    if (threadIdx.x < DBINS) h[threadIdx.x] = 0;
    __syncthreads();
    int n = blockIdx.x * 256 + threadIdx.x;
    if (n < N_NODES) {
        int d = min(hist[n], DBINS - 1);
        atomicAdd(&h[d], 1);
    }
    __syncthreads();
    if (threadIdx.x < DBINS)
        blockhist[blockIdx.x * DBINS + threadIdx.x] = h[threadIdx.x];
}

// K6: column scan over blocks per bin + bin offsets (1 block, 64 threads).
__global__ __launch_bounds__(64) void degsort2_kernel(
    const int* __restrict__ blockhist,
    int* __restrict__ blockbase,
    int* __restrict__ binoff)
{
    __shared__ int tot[DBINS];
    int bin = threadIdx.x;
    int run = 0;
    for (int b = 0; b < NBLK; ++b) {
        int t = blockhist[b * DBINS + bin];
        blockbase[b * DBINS + bin] = run;
        run += t;
    }
    tot[bin] = run;
    __syncthreads();
    if (threadIdx.x == 0) {
        int r = 0;
        for (int k = 0; k < DBINS; ++k) { binoff[k] = r; r += tot[k]; }
    }
}

// K7: scatter node ids into degree-sorted order.
__global__ __launch_bounds__(256) void degsort3_kernel(
    const int* __restrict__ hist,
    const int* __restrict__ blockbase,
    const int* __restrict__ binoff,
    int* __restrict__ nodeorder)
{
    __shared__ int cur[DBINS];
    if (threadIdx.x < DBINS) cur[threadIdx.x] = 0;
    __syncthreads();
    int n = blockIdx.x * 256 + threadIdx.x;
    if (n < N_NODES) {
        int d = min(hist[n], DBINS - 1);
        int l = atomicAdd(&cur[d], 1);
        int pos = binoff[d] + blockbase[blockIdx.x * DBINS + d] + l;
        nodeorder[pos] = n;
    }
}

// ---------------------------------------------------------------------------
// K8: fused gather + node finalize.
// Phase A: 5 threads/node accumulate component t of S[n] = sum outer(v[src],
//          [1,ef]) into registers, stash in LDS.
// Phase B: wave 0 (64 threads, 1 node each) applies enet weights (uniform ->
//          SGPR), mean, root, bias -> out; wave butterfly -> stats atomics.
// ---------------------------------------------------------------------------
__global__ __launch_bounds__(320) void gather_fused_kernel(
    const float* __restrict__ v,
    const int* __restrict__ esrc,
    const float4* __restrict__ eef,
    const int* __restrict__ hist,
    const int* __restrict__ row_part,
    const int* __restrict__ bsum_ex,
    const int* __restrict__ nodeorder,
    const float* __restrict__ enet_w,
    const float* __restrict__ enet_b,
    const float* __restrict__ root,
    const float* __restrict__ bias,
    float* __restrict__ out,
    float* __restrict__ stats)
{
    __shared__ float sacc[64 * SROW];

    // ---------------- Phase A ----------------
    {
        int g = threadIdx.x / 5;
        int t = threadIdx.x % 5;
        int gi = blockIdx.x * 64 + g;
        int n = (gi < N_NODES) ? nodeorder[gi] : -1;

        float acc[16];
        #pragma unroll
        for (int i = 0; i < 16; ++i) acc[i] = 0.0f;

        if (n >= 0) {
            int start = row_part[n] + bsum_ex[n >> 8];
            int deg = hist[n];
            for (int j = 0; j < deg; ++j) {
                int src = esrc[start + j];
                float4 ef = eef[start + j];
                float c = 1.0f;
                c = (t == 1) ? ef.x : c;
                c = (t == 2) ? ef.y : c;
                c = (t == 3) ? ef.z : c;
                c = (t == 4) ? ef.w : c;
                const float* vp = v + (size_t)src * 16;
                #pragma unroll
                for (int i = 0; i < 4; ++i) {
                    float4 tv = *(const float4*)(vp + i * 4);
                    acc[i*4+0] = fmaf(c, tv.x, acc[i*4+0]);
                    acc[i*4+1] = fmaf(c, tv.y, acc[i*4+1]);
                    acc[i*4+2] = fmaf(c, tv.z, acc[i*4+2]);
                    acc[i*4+3] = fmaf(c, tv.w, acc[i*4+3]);
                }
            }
        }
        float* sp = sacc + g * SROW + t * 16;
        #pragma unroll
        for (int m = 0; m < 4; ++m)
            *(float4*)(sp + m * 4) = make_float4(acc[m*4+0], acc[m*4+1],
                                                 acc[m*4+2], acc[m*4+3]);
    }
    __syncthreads();

    // ---------------- Phase B (wave 0 only) ----------------
    if (threadIdx.x < 64) {
        int l = threadIdx.x;
        int gi = blockIdx.x * 64 + l;
        int n = (gi < N_NODES) ? nodeorder[gi] : -1;

        float val[16];
        if (n >= 0) {
            float msg[16];
            #pragma unroll
            for (int o = 0; o < 16; ++o) msg[o] = 0.0f;

            #pragma unroll
            for (int t = 0; t < 5; ++t) {
                float st[16];
                const float* sp = sacc + l * SROW + t * 16;
                #pragma unroll
                for (int m = 0; m < 4; ++m) {
                    float4 tv = *(const float4*)(sp + m * 4);
                    st[m*4+0] = tv.x; st[m*4+1] = tv.y;
                    st[m*4+2] = tv.z; st[m*4+3] = tv.w;
                }
                #pragma unroll
                for (int o = 0; o < 16; ++o) {
                    float a = msg[o];
                    #pragma unroll
                    for (int i = 0; i < 16; ++i) {
                        float w = (t == 0) ? enet_b[i * 16 + o]
                                           : enet_w[(i * 16 + o) * 4 + (t - 1)];
                        a = fmaf(st[i], w, a);
                    }
                    msg[o] = a;
                }
            }

            float scale = 1.0f / fmaxf((float)hist[n], 1.0f);
            float vn[16];
            #pragma unroll
            for (int i = 0; i < 4; ++i) {
                float4 tv = *(const float4*)(v + (size_t)n * 16 + i * 4);
                vn[i*4+0] = tv.x; vn[i*4+1] = tv.y;
                vn[i*4+2] = tv.z; vn[i*4+3] = tv.w;
            }
            #pragma unroll
            for (int o = 0; o < 16; ++o) {
                float a = fmaf(msg[o], scale, bias[o]);
                #pragma unroll
                for (int i = 0; i < 16; ++i)
                    a = fmaf(vn[i], root[i * 16 + o], a);
                val[o] = a;
            }
            #pragma unroll
            for (int i = 0; i < 4; ++i)
                *(float4*)(out + (size_t)n * 16 + i * 4) =
                    make_float4(val[i*4+0], val[i*4+1], val[i*4+2], val[i*4+3]);
        } else {
            #pragma unroll
            for (int o = 0; o < 16; ++o) val[o] = 0.0f;
        }

        // butterfly all-reduce over the single wave
        float ssum[16], ssq[16];
        #pragma unroll
        for (int o = 0; o < 16; ++o) {
            float a = val[o];
            float b = a * a;
            #pragma unroll
            for (int m = 1; m < 64; m <<= 1) {
                a += __shfl_xor(a, m, 64);
                b += __shfl_xor(b, m, 64);
            }
            ssum[o] = a; ssq[o] = b;
        }
        if (l == 0) {
            #pragma unroll
            for (int o = 0; o < 16; ++o) {
                unsafeAtomicAdd(stats + o, ssum[o]);
                unsafeAtomicAdd(stats + 16 + o, ssq[o]);
            }
        }
    }
}

// K9: BatchNorm (batch stats) + LeakyReLU, in place on d_out.
__global__ __launch_bounds__(256) void final_kernel(
    float* __restrict__ out,
    const float* __restrict__ stats,
    const float* __restrict__ gamma,
    const float* __restrict__ beta)
{
    int idx = blockIdx.x * 256 + threadIdx.x;
    if (idx >= N_NODES * 16) return;
    int o = idx & 15;
    const float invN = 1.0f / (float)N_NODES;
    float mu = stats[o] * invN;
    float var = stats[16 + o] * invN - mu * mu;
    var = fmaxf(var, 0.0f);
    float x = out[idx];
    float y = fmaf(gamma[o] * (x - mu), rsqrtf(var + EPS), beta[o]);
    out[idx] = (y >= 0.0f) ? y : SLOPE * y;
}

extern "C" void kernel_launch(void* const* d_in, const int* in_sizes, int n_in,
                              void* d_out, int out_size, void* d_ws, size_t ws_size,
                              hipStream_t stream)
{
    const float* v = (const float*)d_in[0];
    const float* e = (const float*)d_in[1];
    const int* edge_index = (const int*)d_in[2];
    const float* enet_w = (const float*)d_in[3];
    const float* enet_b = (const float*)d_in[4];
    const float* root = (const float*)d_in[5];
    const float* bias = (const float*)d_in[6];
    const float* gamma = (const float*)d_in[7];
    const float* beta = (const float*)d_in[8];
    float* out = (float*)d_out;

    char* ws = (char*)d_ws;
    float4* eef     = (float4*)ws;                 ws += (size_t)N_EDGES * 16;
    int*   rank     = (int*)ws;                    ws += (size_t)N_EDGES * 4;
    int*   esrc     = (int*)ws;                    ws += (size_t)N_EDGES * 4;
    int*   hist     = (int*)ws;                    ws += (size_t)N_NODES * 4;
    float* stats    = (float*)ws;                  ws += 32 * 4;
    int*   row_part = (int*)ws;                    ws += (size_t)N_NODES * 4;
    int*   nodeorder= (int*)ws;                    ws += (size_t)N_NODES * 4;
    int*   blockhist= (int*)ws;                    ws += (size_t)NBLK * DBINS * 4;
    int*   blockbase= (int*)ws;                    ws += (size_t)NBLK * DBINS * 4;
    int*   bsum     = (int*)ws;                    ws += 512 * 4;
    int*   bsum_ex  = (int*)ws;                    ws += 512 * 4;
    int*   binoff   = (int*)ws;

    // zero hist + stats (contiguous)
    hipMemsetAsync(hist, 0, (size_t)N_NODES * 4 + 32 * 4, stream);

    rank_kernel<<<(N_EDGES + 255) / 256, 256, 0, stream>>>(edge_index, hist, rank);
    scan1_kernel<<<NBLK, 256, 0, stream>>>(hist, row_part, bsum);
    scan2_kernel<<<1, 512, 0, stream>>>(bsum, bsum_ex);
    payload_kernel<<<(N_EDGES + 255) / 256, 256, 0, stream>>>(
        edge_index, e, rank, row_part, bsum_ex, esrc, eef);
    degsort1_kernel<<<NBLK, 256, 0, stream>>>(hist, blockhist);
    degsort2_kernel<<<1, 64, 0, stream>>>(blockhist, blockbase, binoff);
    degsort3_kernel<<<NBLK, 256, 0, stream>>>(hist, blockbase, binoff, nodeorder);
    gather_fused_kernel<<<GBLK, 320, 0, stream>>>(
        v, esrc, eef, hist, row_part, bsum_ex, nodeorder,
        enet_w, enet_b, root, bias, out, stats);
    final_kernel<<<(N_NODES * 16 + 255) / 256, 256, 0, stream>>>(
        out, stats, gamma, beta);
}

// Round 6
// 272.365 us; speedup vs baseline: 2.8061x; 2.8061x over previous
//
#include <hip/hip_runtime.h>

#define N_NODES 100000
#define N_EDGES 1000000
#define EPS 1e-5f
#define SLOPE 0.01f
#define NBLK 391   // ceil(N_NODES/256)
#define GBLK 1563  // ceil(N_NODES*5/320): gather, 5 thr/node, 320/block

// ---------------------------------------------------------------------------
// ws layout: eef(float4 E, 16MB) | esrc(E, 4MB) | hist(N)+stats(32) [zeroed] |
//            row_ptr(N) | cursor(N) | bsum(512) | bsum_ex(512) | S(N*80, 32MB)
// total ~53.6 MB
//
// Natural node order everywhere (round-5 lesson: degree-sorting kills CSR
// locality and creates a serial high-degree tail; i.i.d. degrees inside a
// wave are already balanced enough).
// ---------------------------------------------------------------------------

// K1: in-degree histogram (1M no-return memory-side atomics).
__global__ __launch_bounds__(256) void count_kernel(
    const int* __restrict__ edge_index,
    int* __restrict__ hist)
{
    int eid = blockIdx.x * 256 + threadIdx.x;
    if (eid >= N_EDGES) return;
    atomicAdd(hist + edge_index[N_EDGES + eid], 1);
}

// K2: block-local exclusive scan of hist -> row_ptr (partial) + block sums.
__global__ __launch_bounds__(256) void scan1_kernel(
    const int* __restrict__ hist,
    int* __restrict__ row_ptr,
    int* __restrict__ bsum)
{
    __shared__ int s[256];
    int tid = threadIdx.x;
    int idx = blockIdx.x * 256 + tid;
    int val = (idx < N_NODES) ? hist[idx] : 0;
    s[tid] = val;
    __syncthreads();
    #pragma unroll
    for (int off = 1; off < 256; off <<= 1) {
        int t = (tid >= off) ? s[tid - off] : 0;
        __syncthreads();
        s[tid] += t;
        __syncthreads();
    }
    if (idx < N_NODES) row_ptr[idx] = s[tid] - val;  // block-local exclusive
    if (tid == 255) bsum[blockIdx.x] = s[255];
}

// K3: exclusive scan of block sums (single block).
__global__ __launch_bounds__(512) void scan2_kernel(
    const int* __restrict__ bsum,
    int* __restrict__ bsum_ex)
{
    __shared__ int s[512];
    int tid = threadIdx.x;
    int val = (tid < NBLK) ? bsum[tid] : 0;
    s[tid] = val;
    __syncthreads();
    #pragma unroll
    for (int off = 1; off < 512; off <<= 1) {
        int t = (tid >= off) ? s[tid - off] : 0;
        __syncthreads();
        s[tid] += t;
        __syncthreads();
    }
    bsum_ex[tid] = s[tid] - val;
}

// K4: absolute row starts; cursor = mutable copy for the scatter fetch-add.
__global__ __launch_bounds__(256) void cursor_kernel(
    const int* __restrict__ bsum_ex,
    int* __restrict__ row_ptr,
    int* __restrict__ cursor)
{
    int n = blockIdx.x * 256 + threadIdx.x;
    if (n >= N_NODES) return;
    int s = row_ptr[n] + bsum_ex[n >> 8];
    row_ptr[n] = s;
    cursor[n] = s;
}

// K5: scatter edge payload (src, ef) into CSR slots via cursor fetch-add.
// After this kernel, cursor[n] == row end. Within-row order is
// non-deterministic -> fp-sum reassociation only (well within tolerance).
__global__ __launch_bounds__(256) void payload_kernel(
    const int* __restrict__ edge_index,
    const float* __restrict__ efeat,
    int* __restrict__ cursor,
    int* __restrict__ esrc,
    float4* __restrict__ eef)
{
    int eid = blockIdx.x * 256 + threadIdx.x;
    if (eid >= N_EDGES) return;
    int dst = edge_index[N_EDGES + eid];
    int slot = atomicAdd(cursor + dst, 1);
    esrc[slot] = edge_index[eid];
    eef[slot] = *(const float4*)(efeat + (size_t)eid * 4);
}

// ---------------------------------------------------------------------------
// K6: S[n] = sum over incoming edges of outer(v[src], [1, ef]).
// 5 threads/node (natural order); thread t owns component t (16 floats).
// esrc/eef stream sequentially per row; only v[src] is random (cache-warm).
// ---------------------------------------------------------------------------
__global__ __launch_bounds__(320) void gather_s_kernel(
    const float* __restrict__ v,
    const int* __restrict__ esrc,
    const float4* __restrict__ eef,
    const int* __restrict__ row_ptr,
    const int* __restrict__ row_end,
    float* __restrict__ S)
{
    int tid = blockIdx.x * 320 + threadIdx.x;
    int n = tid / 5;
    int t = tid % 5;
    if (n >= N_NODES) return;

    int start = row_ptr[n];
    int end = row_end[n];

    float acc[16];
    #pragma unroll
    for (int i = 0; i < 16; ++i) acc[i] = 0.0f;

    for (int j = start; j < end; ++j) {
        int src = esrc[j];
        float4 ef = eef[j];
        float c = 1.0f;
        c = (t == 1) ? ef.x : c;
        c = (t == 2) ? ef.y : c;
        c = (t == 3) ? ef.z : c;
        c = (t == 4) ? ef.w : c;
        const float* vp = v + (size_t)src * 16;
        #pragma unroll
        for (int i = 0; i < 4; ++i) {
            float4 tv = *(const float4*)(vp + i * 4);
            acc[i*4+0] = fmaf(c, tv.x, acc[i*4+0]);
            acc[i*4+1] = fmaf(c, tv.y, acc[i*4+1]);
            acc[i*4+2] = fmaf(c, tv.z, acc[i*4+2]);
            acc[i*4+3] = fmaf(c, tv.w, acc[i*4+3]);
        }
    }

    float* sp = S + (size_t)n * 80 + t * 16;
    #pragma unroll
    for (int i = 0; i < 4; ++i)
        *(float4*)(sp + i * 4) = make_float4(acc[i*4+0], acc[i*4+1],
                                             acc[i*4+2], acc[i*4+3]);
}

// ---------------------------------------------------------------------------
// K7: per-node: msg = (S0*B + sum_k Sk*Wk)/deg; + root*v + bias -> out;
// per-column sum/sumsq -> stats. Weight indices wave-uniform -> SGPR folds.
// ---------------------------------------------------------------------------
__global__ __launch_bounds__(256) void node_kernel(
    const float* __restrict__ v,
    const float* __restrict__ S,
    const int* __restrict__ row_ptr,
    const int* __restrict__ row_end,
    const float* __restrict__ enet_w,
    const float* __restrict__ enet_b,
    const float* __restrict__ root,
    const float* __restrict__ bias,
    float* __restrict__ out,
    float* __restrict__ stats)
{
    int n = blockIdx.x * 256 + threadIdx.x;
    bool active = (n < N_NODES);

    float val[16];
    if (active) {
        float s[80];
        #pragma unroll
        for (int i = 0; i < 20; ++i) {
            float4 tv = *(const float4*)(S + (size_t)n * 80 + i * 4);
            s[i*4+0] = tv.x; s[i*4+1] = tv.y; s[i*4+2] = tv.z; s[i*4+3] = tv.w;
        }
        float vn[16];
        #pragma unroll
        for (int i = 0; i < 4; ++i) {
            float4 tv = *(const float4*)(v + (size_t)n * 16 + i * 4);
            vn[i*4+0] = tv.x; vn[i*4+1] = tv.y; vn[i*4+2] = tv.z; vn[i*4+3] = tv.w;
        }
        float deg = (float)(row_end[n] - row_ptr[n]);
        float scale = 1.0f / fmaxf(deg, 1.0f);

        #pragma unroll
        for (int o = 0; o < 16; ++o) {
            float a = 0.0f;
            #pragma unroll
            for (int i = 0; i < 16; ++i) {
                a = fmaf(s[i], enet_b[i * 16 + o], a);           // S0 * B
                #pragma unroll
                for (int k = 0; k < 4; ++k)
                    a = fmaf(s[16 + k * 16 + i],
                             enet_w[(i * 16 + o) * 4 + k], a);   // Sk * Wk
            }
            a = fmaf(a, scale, bias[o]);
            #pragma unroll
            for (int i = 0; i < 16; ++i)
                a = fmaf(vn[i], root[i * 16 + o], a);
            val[o] = a;
        }
        #pragma unroll
        for (int i = 0; i < 4; ++i)
            *(float4*)(out + (size_t)n * 16 + i * 4) =
                make_float4(val[i*4+0], val[i*4+1], val[i*4+2], val[i*4+3]);
    } else {
        #pragma unroll
        for (int o = 0; o < 16; ++o) val[o] = 0.0f;
    }

    // wave butterfly + LDS reduction of sum / sumsq per column
    float ssum[16], ssq[16];
    #pragma unroll
    for (int o = 0; o < 16; ++o) {
        float a = val[o];
        float b = a * a;
        #pragma unroll
        for (int m = 1; m < 64; m <<= 1) {
            a += __shfl_xor(a, m, 64);
            b += __shfl_xor(b, m, 64);
        }
        ssum[o] = a; ssq[o] = b;
    }
    __shared__ float part[4][32];
    int wave = threadIdx.x >> 6;
    int lane = threadIdx.x & 63;
    if (lane == 0) {
        #pragma unroll
        for (int o = 0; o < 16; ++o) {
            part[wave][o] = ssum[o];
            part[wave][16 + o] = ssq[o];
        }
    }
    __syncthreads();
    if (threadIdx.x < 32) {
        float t = part[0][threadIdx.x] + part[1][threadIdx.x] +
                  part[2][threadIdx.x] + part[3][threadIdx.x];
        unsafeAtomicAdd(stats + threadIdx.x, t);
    }
}

// K8: BatchNorm (batch stats) + LeakyReLU, in place on d_out.
__global__ __launch_bounds__(256) void final_kernel(
    float* __restrict__ out,
    const float* __restrict__ stats,
    const float* __restrict__ gamma,
    const float* __restrict__ beta)
{
    int idx = blockIdx.x * 256 + threadIdx.x;
    if (idx >= N_NODES * 16) return;
    int o = idx & 15;
    const float invN = 1.0f / (float)N_NODES;
    float mu = stats[o] * invN;
    float var = stats[16 + o] * invN - mu * mu;
    var = fmaxf(var, 0.0f);
    float x = out[idx];
    float y = fmaf(gamma[o] * (x - mu), rsqrtf(var + EPS), beta[o]);
    out[idx] = (y >= 0.0f) ? y : SLOPE * y;
}

extern "C" void kernel_launch(void* const* d_in, const int* in_sizes, int n_in,
                              void* d_out, int out_size, void* d_ws, size_t ws_size,
                              hipStream_t stream)
{
    const float* v = (const float*)d_in[0];
    const float* e = (const float*)d_in[1];
    const int* edge_index = (const int*)d_in[2];
    const float* enet_w = (const float*)d_in[3];
    const float* enet_b = (const float*)d_in[4];
    const float* root = (const float*)d_in[5];
    const float* bias = (const float*)d_in[6];
    const float* gamma = (const float*)d_in[7];
    const float* beta = (const float*)d_in[8];
    float* out = (float*)d_out;

    char* ws = (char*)d_ws;
    float4* eef    = (float4*)ws;               ws += (size_t)N_EDGES * 16;
    int*   esrc    = (int*)ws;                  ws += (size_t)N_EDGES * 4;
    int*   hist    = (int*)ws;                  ws += (size_t)N_NODES * 4;
    float* stats   = (float*)ws;                ws += 32 * 4;
    int*   row_ptr = (int*)ws;                  ws += (size_t)N_NODES * 4;
    int*   cursor  = (int*)ws;                  ws += (size_t)N_NODES * 4;
    int*   bsum    = (int*)ws;                  ws += 512 * 4;
    int*   bsum_ex = (int*)ws;                  ws += 512 * 4;
    float* S       = (float*)ws;

    // zero hist + stats (contiguous)
    hipMemsetAsync(hist, 0, (size_t)N_NODES * 4 + 32 * 4, stream);

    count_kernel<<<(N_EDGES + 255) / 256, 256, 0, stream>>>(edge_index, hist);
    scan1_kernel<<<NBLK, 256, 0, stream>>>(hist, row_ptr, bsum);
    scan2_kernel<<<1, 512, 0, stream>>>(bsum, bsum_ex);
    cursor_kernel<<<NBLK, 256, 0, stream>>>(bsum_ex, row_ptr, cursor);
    payload_kernel<<<(N_EDGES + 255) / 256, 256, 0, stream>>>(
        edge_index, e, cursor, esrc, eef);
    gather_s_kernel<<<GBLK, 320, 0, stream>>>(
        v, esrc, eef, row_ptr, cursor, S);
    node_kernel<<<NBLK, 256, 0, stream>>>(
        v, S, row_ptr, cursor, enet_w, enet_b, root, bias, out, stats);
    final_kernel<<<(N_NODES * 16 + 255) / 256, 256, 0, stream>>>(
        out, stats, gamma, beta);
}